// Round 1
// baseline (2962.287 us; speedup 1.0000x reference)
//
#include <hip/hip_runtime.h>
#include <math.h>

#define B_SZ 4
#define C_SZ 512
#define N_SZ 4096
#define D_SZ 64

// ---------------------------------------------------------------------------
// Kernel 1: per-query-row softmax stats (max, sum of exp) over all keys.
// Block = 256 threads, handles 64 query rows (m0..m0+63).
// Thread t: mi = t&63 (its row), tc = t>>6 (its n-phase: n%32 in [8*tc, 8*tc+8)).
// b-row lives in registers; c staged 32 rows at a time into LDS.
// ---------------------------------------------------------------------------
__global__ __launch_bounds__(256) void stats_kernel(
    const float* __restrict__ bmat, const float* __restrict__ cmat,
    float* __restrict__ row_max, float* __restrict__ row_sum)
{
    const int batch = blockIdx.z;
    const int m0 = blockIdx.x * 64;
    const int t = threadIdx.x;
    const int mi = t & 63;
    const int tc = t >> 6;
    const int nb = tc * 8;

    // load this thread's b row (64 floats) into registers
    float4 breg[16];
    const float4* bp = (const float4*)(bmat + ((size_t)batch * N_SZ + (m0 + mi)) * D_SZ);
#pragma unroll
    for (int i = 0; i < 16; ++i) breg[i] = bp[i];

    __shared__ __align__(16) float sm_c[32 * 64];

    float mloc = -INFINITY;
    float lloc = 0.0f;

    for (int n0 = 0; n0 < N_SZ; n0 += 32) {
        // stage c[n0..n0+31][0..63] (8 KB, contiguous) into LDS
        const float4* cp = (const float4*)(cmat + ((size_t)batch * N_SZ + n0) * D_SZ);
        float4* smc4 = (float4*)sm_c;
        smc4[t] = cp[t];
        smc4[t + 256] = cp[t + 256];
        __syncthreads();

        float s[8];
#pragma unroll
        for (int k = 0; k < 8; ++k) s[k] = 0.0f;
#pragma unroll
        for (int d4 = 0; d4 < 16; ++d4) {
            float4 bv = breg[d4];
#pragma unroll
            for (int k = 0; k < 8; ++k) {
                float4 cv = ((const float4*)(sm_c + (nb + k) * 64))[d4];  // broadcast
                s[k] = fmaf(bv.x, cv.x, s[k]);
                s[k] = fmaf(bv.y, cv.y, s[k]);
                s[k] = fmaf(bv.z, cv.z, s[k]);
                s[k] = fmaf(bv.w, cv.w, s[k]);
            }
        }
        // online max/sum update over this thread's 8 keys
#pragma unroll
        for (int k = 0; k < 8; ++k) {
            float sv = s[k];
            float nm = fmaxf(mloc, sv);
            lloc = lloc * __expf(mloc - nm) + __expf(sv - nm);
            mloc = nm;
        }
        __syncthreads();
    }

    // combine the 4 partial (m,l) pairs per row
    __shared__ float redm[4][64];
    __shared__ float redl[4][64];
    redm[tc][mi] = mloc;
    redl[tc][mi] = lloc;
    __syncthreads();
    if (tc == 0) {
        float m0v = redm[0][mi], m1v = redm[1][mi], m2v = redm[2][mi], m3v = redm[3][mi];
        float M = fmaxf(fmaxf(m0v, m1v), fmaxf(m2v, m3v));
        float L = redl[0][mi] * __expf(m0v - M) + redl[1][mi] * __expf(m1v - M) +
                  redl[2][mi] * __expf(m2v - M) + redl[3][mi] * __expf(m3v - M);
        row_max[(size_t)batch * N_SZ + m0 + mi] = M;
        row_sum[(size_t)batch * N_SZ + m0 + mi] = L;
    }
}

// ---------------------------------------------------------------------------
// Kernel 2: out[b, ch, m] = sum_n softmax(b_m . c_n) * a[b, ch, n] + a[b, ch, m]
// Block = 256 threads, tile = 64 m-rows x 128 channels.
// Thread t: mi = t&63 (its m-row, fixed), tc = t>>6; its 32 channels are
// ch0 + tc*32 + j (j=0..31). Per 32-key tile: recompute scores (b in regs,
// c in LDS), P to LDS (stride 33, conflict-free), accumulate P.V with
// V = a staged transposed in LDS (broadcast float4 reads).
// ---------------------------------------------------------------------------
__global__ __launch_bounds__(256) void pv_kernel(
    const float* __restrict__ amat, const float* __restrict__ bmat,
    const float* __restrict__ cmat,
    const float* __restrict__ row_max, const float* __restrict__ row_sum,
    float* __restrict__ out)
{
    const int batch = blockIdx.z;
    const int m0 = blockIdx.x * 64;
    const int ch0 = blockIdx.y * 128;
    const int t = threadIdx.x;
    const int mi = t & 63;
    const int tc = t >> 6;
    const int nb = tc * 8;

    float4 breg[16];
    const float4* bp = (const float4*)(bmat + ((size_t)batch * N_SZ + (m0 + mi)) * D_SZ);
#pragma unroll
    for (int i = 0; i < 16; ++i) breg[i] = bp[i];

    const float rmax = row_max[(size_t)batch * N_SZ + m0 + mi];
    const float rinv = 1.0f / row_sum[(size_t)batch * N_SZ + m0 + mi];

    __shared__ __align__(16) float sm_c[32 * 64];     // 8 KB
    __shared__ __align__(16) float sm_v[32 * 128];    // 16 KB: V[nn][cc]
    __shared__ float sm_p[64 * 33];                   // 8.25 KB, padded

    float acc[32];
#pragma unroll
    for (int j = 0; j < 32; ++j) acc[j] = 0.0f;

    const int cc = t >> 1;       // channel this thread loads for V-staging
    const int half = t & 1;      // which 16-key half it loads

    for (int n0 = 0; n0 < N_SZ; n0 += 32) {
        // stage c tile
        const float4* cp = (const float4*)(cmat + ((size_t)batch * N_SZ + n0) * D_SZ);
        float4* smc4 = (float4*)sm_c;
        smc4[t] = cp[t];
        smc4[t + 256] = cp[t + 256];

        // stage V tile: sm_v[nn][cc] = a[batch][ch0+cc][n0+nn]
        {
            const float* ap = amat + (size_t)batch * C_SZ * N_SZ + (size_t)(ch0 + cc) * N_SZ
                              + n0 + half * 16;
            const float4* ap4 = (const float4*)ap;
#pragma unroll
            for (int q = 0; q < 4; ++q) {
                float4 v = ap4[q];
                int nn = half * 16 + q * 4;
                sm_v[(nn + 0) * 128 + cc] = v.x;
                sm_v[(nn + 1) * 128 + cc] = v.y;
                sm_v[(nn + 2) * 128 + cc] = v.z;
                sm_v[(nn + 3) * 128 + cc] = v.w;
            }
        }
        __syncthreads();

        // scores for this thread's 8 keys
        float s[8];
#pragma unroll
        for (int k = 0; k < 8; ++k) s[k] = 0.0f;
#pragma unroll
        for (int d4 = 0; d4 < 16; ++d4) {
            float4 bv = breg[d4];
#pragma unroll
            for (int k = 0; k < 8; ++k) {
                float4 cv = ((const float4*)(sm_c + (nb + k) * 64))[d4];  // broadcast
                s[k] = fmaf(bv.x, cv.x, s[k]);
                s[k] = fmaf(bv.y, cv.y, s[k]);
                s[k] = fmaf(bv.z, cv.z, s[k]);
                s[k] = fmaf(bv.w, cv.w, s[k]);
            }
        }
#pragma unroll
        for (int k = 0; k < 8; ++k) {
            sm_p[mi * 33 + nb + k] = __expf(s[k] - rmax) * rinv;
        }
        __syncthreads();

        // accumulate P.V over the 32 keys of this tile
#pragma unroll 4
        for (int nn = 0; nn < 32; ++nn) {
            float pv = sm_p[mi * 33 + nn];
            const float4* vrow = (const float4*)(sm_v + nn * 128 + tc * 32);
#pragma unroll
            for (int jj = 0; jj < 8; ++jj) {
                float4 v = vrow[jj];  // broadcast within wave
                acc[jj * 4 + 0] = fmaf(pv, v.x, acc[jj * 4 + 0]);
                acc[jj * 4 + 1] = fmaf(pv, v.y, acc[jj * 4 + 1]);
                acc[jj * 4 + 2] = fmaf(pv, v.z, acc[jj * 4 + 2]);
                acc[jj * 4 + 3] = fmaf(pv, v.w, acc[jj * 4 + 3]);
            }
        }
        __syncthreads();
    }

    // epilogue: out[b][ch][m] = acc + a[b][ch][m]   (coalesced over mi)
    const size_t base = (size_t)batch * C_SZ * N_SZ + (size_t)(ch0 + tc * 32) * N_SZ + (m0 + mi);
#pragma unroll
    for (int j = 0; j < 32; ++j) {
        float r = amat[base + (size_t)j * N_SZ];
        out[base + (size_t)j * N_SZ] = acc[j] + r;
    }
}

extern "C" void kernel_launch(void* const* d_in, const int* in_sizes, int n_in,
                              void* d_out, int out_size, void* d_ws, size_t ws_size,
                              hipStream_t stream) {
    const float* a = (const float*)d_in[0];
    const float* b = (const float*)d_in[1];
    const float* c = (const float*)d_in[2];
    float* out = (float*)d_out;

    float* row_max = (float*)d_ws;
    float* row_sum = row_max + (size_t)B_SZ * N_SZ;

    dim3 blk(256);
    stats_kernel<<<dim3(N_SZ / 64, 1, B_SZ), blk, 0, stream>>>(b, c, row_max, row_sum);
    pv_kernel<<<dim3(N_SZ / 64, C_SZ / 128, B_SZ), blk, 0, stream>>>(
        a, b, c, row_max, row_sum, out);
}

// Round 3
// 320.994 us; speedup vs baseline: 9.2285x; 9.2285x over previous
//
#include <hip/hip_runtime.h>
#include <math.h>

#define B_SZ 4
#define C_SZ 512
#define N_SZ 4096
#define D_SZ 64

typedef __attribute__((ext_vector_type(4))) float f32x4;
typedef __attribute__((ext_vector_type(8))) short bf16x8;

// fp32 -> bf16 with round-to-nearest-even
__device__ __forceinline__ short f2bf(float x) {
    union { float f; unsigned u; } v; v.f = x;
    unsigned r = v.u + 0x7FFFu + ((v.u >> 16) & 1u);
    return (short)(r >> 16);
}
__device__ __forceinline__ float bf2f(short h) {
    union { float f; unsigned u; } v; v.u = ((unsigned)(unsigned short)h) << 16;
    return v.f;
}

__device__ __forceinline__ bf16x8 pack8(float4 a, float4 b) {
    bf16x8 r;
    r[0] = f2bf(a.x); r[1] = f2bf(a.y); r[2] = f2bf(a.z); r[3] = f2bf(a.w);
    r[4] = f2bf(b.x); r[5] = f2bf(b.y); r[6] = f2bf(b.z); r[7] = f2bf(b.w);
    return r;
}

// split 8 fp32 into bf16 hi + bf16 lo (residual) — ~fp32 accuracy when recombined
__device__ __forceinline__ void split8(float4 a, float4 b, bf16x8* hi, bf16x8* lo) {
    float v[8] = {a.x, a.y, a.z, a.w, b.x, b.y, b.z, b.w};
    bf16x8 h, l;
#pragma unroll
    for (int i = 0; i < 8; ++i) {
        short hh = f2bf(v[i]);
        h[i] = hh;
        l[i] = f2bf(v[i] - bf2f(hh));
    }
    *hi = h; *lo = l;
}

// ---------------------------------------------------------------------------
// Pass 1: softmax stats with hi/lo split-bf16 scores.
// Block = 256 thr (4 waves), each wave owns 64 m-rows.
// Grid: (m-tiles=16, n-slices=4, B).
// ---------------------------------------------------------------------------
__global__ __launch_bounds__(256) void stats_kernel(
    const float* __restrict__ bmat, const float* __restrict__ cmat,
    float* __restrict__ partM, float* __restrict__ partL)
{
    const int t = threadIdx.x;
    const int lane = t & 63;
    const int l15 = lane & 15;
    const int lg = lane >> 4;
    const int w = t >> 6;
    const int bz = blockIdx.z;
    const int m0 = blockIdx.x * 256 + w * 64;
    const int nbeg = blockIdx.y * 1024;

    __shared__ __align__(16) short smc_hi[64 * 72];
    __shared__ __align__(16) short smc_lo[64 * 72];

    bf16x8 qh[4][2], ql[4][2];
#pragma unroll
    for (int mf = 0; mf < 4; ++mf)
#pragma unroll
        for (int kf = 0; kf < 2; ++kf) {
            const float* qp = bmat + ((size_t)bz * N_SZ + m0 + mf * 16 + l15) * D_SZ
                              + kf * 32 + lg * 8;
            float4 q0 = ((const float4*)qp)[0];
            float4 q1 = ((const float4*)qp)[1];
            split8(q0, q1, &qh[mf][kf], &ql[mf][kf]);
        }

    float M[4][4], L[4][4];
#pragma unroll
    for (int mf = 0; mf < 4; ++mf)
#pragma unroll
        for (int r = 0; r < 4; ++r) { M[mf][r] = -1e30f; L[mf][r] = 0.0f; }

    for (int n0 = nbeg; n0 < nbeg + 1024; n0 += 64) {
        __syncthreads();
        {   // stage c chunk [64 n][64 d] fp32 -> bf16 hi/lo, pitch 72
            const int nn = t >> 2, d0 = (t & 3) * 16;
            const float* cp = cmat + ((size_t)bz * N_SZ + n0 + nn) * D_SZ + d0;
            float4 c0 = ((const float4*)cp)[0];
            float4 c1 = ((const float4*)cp)[1];
            float4 c2 = ((const float4*)cp)[2];
            float4 c3 = ((const float4*)cp)[3];
            bf16x8 h, l;
            split8(c0, c1, &h, &l);
            *(bf16x8*)&smc_hi[nn * 72 + d0] = h;
            *(bf16x8*)&smc_lo[nn * 72 + d0] = l;
            split8(c2, c3, &h, &l);
            *(bf16x8*)&smc_hi[nn * 72 + d0 + 8] = h;
            *(bf16x8*)&smc_lo[nn * 72 + d0 + 8] = l;
        }
        __syncthreads();

        bf16x8 kh[4][2], kl[4][2];
#pragma unroll
        for (int nf = 0; nf < 4; ++nf)
#pragma unroll
            for (int kf = 0; kf < 2; ++kf) {
                kh[nf][kf] = *(const bf16x8*)&smc_hi[(nf * 16 + l15) * 72 + kf * 32 + lg * 8];
                kl[nf][kf] = *(const bf16x8*)&smc_lo[(nf * 16 + l15) * 72 + kf * 32 + lg * 8];
            }

#pragma unroll
        for (int mf = 0; mf < 4; ++mf) {
            f32x4 sv[4];
#pragma unroll
            for (int nf = 0; nf < 4; ++nf) {
                f32x4 s = {0.f, 0.f, 0.f, 0.f};
                s = __builtin_amdgcn_mfma_f32_16x16x32_bf16(qh[mf][0], kh[nf][0], s, 0, 0, 0);
                s = __builtin_amdgcn_mfma_f32_16x16x32_bf16(qh[mf][1], kh[nf][1], s, 0, 0, 0);
                s = __builtin_amdgcn_mfma_f32_16x16x32_bf16(ql[mf][0], kh[nf][0], s, 0, 0, 0);
                s = __builtin_amdgcn_mfma_f32_16x16x32_bf16(ql[mf][1], kh[nf][1], s, 0, 0, 0);
                s = __builtin_amdgcn_mfma_f32_16x16x32_bf16(qh[mf][0], kl[nf][0], s, 0, 0, 0);
                s = __builtin_amdgcn_mfma_f32_16x16x32_bf16(qh[mf][1], kl[nf][1], s, 0, 0, 0);
                sv[nf] = s;
            }
#pragma unroll
            for (int r = 0; r < 4; ++r) {
                float cmax = fmaxf(fmaxf(sv[0][r], sv[1][r]), fmaxf(sv[2][r], sv[3][r]));
                float nm = fmaxf(M[mf][r], cmax);
                float l = L[mf][r] * __expf(M[mf][r] - nm);
                l += __expf(sv[0][r] - nm);
                l += __expf(sv[1][r] - nm);
                l += __expf(sv[2][r] - nm);
                l += __expf(sv[3][r] - nm);
                L[mf][r] = l; M[mf][r] = nm;
            }
        }
    }

    // butterfly reduce across the 16 lanes of each lg-group
#pragma unroll
    for (int mf = 0; mf < 4; ++mf)
#pragma unroll
        for (int r = 0; r < 4; ++r) {
            float m = M[mf][r], l = L[mf][r];
#pragma unroll
            for (int k = 1; k < 16; k <<= 1) {
                float mo = __shfl_xor(m, k, 64);
                float lo = __shfl_xor(l, k, 64);
                float nm = fmaxf(m, mo);
                l = l * __expf(m - nm) + lo * __expf(mo - nm);
                m = nm;
            }
            M[mf][r] = m; L[mf][r] = l;
        }

    if (l15 == 0) {
#pragma unroll
        for (int mf = 0; mf < 4; ++mf)
#pragma unroll
            for (int r = 0; r < 4; ++r) {
                int row = m0 + mf * 16 + lg * 4 + r;
                size_t idx = ((size_t)bz * N_SZ + row) * 4 + blockIdx.y;
                partM[idx] = M[mf][r];
                partL[idx] = L[mf][r];
            }
    }
}

// ---------------------------------------------------------------------------
// Pass 1b: combine 4 n-slice partials -> rmax, 1/L
// ---------------------------------------------------------------------------
__global__ __launch_bounds__(256) void combine_kernel(
    const float* __restrict__ partM, const float* __restrict__ partL,
    float* __restrict__ rmax, float* __restrict__ rinv)
{
    int i = blockIdx.x * 256 + threadIdx.x;
    const float* pm = partM + (size_t)i * 4;
    const float* pl = partL + (size_t)i * 4;
    float m0 = pm[0], m1 = pm[1], m2 = pm[2], m3 = pm[3];
    float m = fmaxf(fmaxf(m0, m1), fmaxf(m2, m3));
    float l = pl[0] * __expf(m0 - m) + pl[1] * __expf(m1 - m) +
              pl[2] * __expf(m2 - m) + pl[3] * __expf(m3 - m);
    rmax[i] = m;
    rinv[i] = 1.0f / l;
}

// ---------------------------------------------------------------------------
// Pass 2: out[b,ch,m] = (sum_n exp(S[m,n]-rmax[m]) * a[b,ch,n]) * rinv[m] + a[b,ch,m]
// Block = 512 thr (8 waves: wm = w&1 (m 64-range), wch = w>>1 (ch 64-range)).
// Block tile: 256 ch x 128 m. Scores recomputed with the SAME hi/lo split +
// MFMA order as stats_kernel (bit-consistent with rmax/rinv).
// ---------------------------------------------------------------------------
__global__ __launch_bounds__(512) void pv_kernel(
    const float* __restrict__ amat, const float* __restrict__ bmat,
    const float* __restrict__ cmat,
    const float* __restrict__ rmax, const float* __restrict__ rinv,
    float* __restrict__ out)
{
    const int t = threadIdx.x;
    const int lane = t & 63;
    const int l15 = lane & 15;
    const int lg = lane >> 4;
    const int w = t >> 6;
    const int wm = w & 1;
    const int wch = w >> 1;
    const int bz = blockIdx.z;
    const int gm0 = blockIdx.x * 128;
    const int gc0 = blockIdx.y * 256;

    __shared__ __align__(16) short smc_hi[64 * 72];  // c chunk [n][d] hi
    __shared__ __align__(16) short smc_lo[64 * 72];  // c chunk [n][d] lo
    __shared__ __align__(16) short sma[256 * 72];    // a chunk [ch][n]
    __shared__ __align__(16) short smp[128 * 72];    // P [m][n]

    const int mbase = gm0 + wm * 64;

    bf16x8 qh[4][2], ql[4][2];
#pragma unroll
    for (int mf = 0; mf < 4; ++mf)
#pragma unroll
        for (int kf = 0; kf < 2; ++kf) {
            const float* qp = bmat + ((size_t)bz * N_SZ + mbase + mf * 16 + l15) * D_SZ
                              + kf * 32 + lg * 8;
            float4 q0 = ((const float4*)qp)[0];
            float4 q1 = ((const float4*)qp)[1];
            split8(q0, q1, &qh[mf][kf], &ql[mf][kf]);
        }

    float rm[4][4];
#pragma unroll
    for (int mf = 0; mf < 4; ++mf)
#pragma unroll
        for (int r = 0; r < 4; ++r)
            rm[mf][r] = rmax[(size_t)bz * N_SZ + mbase + mf * 16 + lg * 4 + r];

    f32x4 acc[4][4];
#pragma unroll
    for (int i = 0; i < 4; ++i)
#pragma unroll
        for (int j = 0; j < 4; ++j)
            acc[i][j] = (f32x4){0.f, 0.f, 0.f, 0.f};

    const int c_nn = t >> 3, c_d0 = (t & 7) * 8;
    const int a_cc = t >> 1, a_nb = (t & 1) * 32;
    const float* cp_base = cmat + ((size_t)bz * N_SZ + c_nn) * D_SZ + c_d0;
    const float* ap_base = amat + ((size_t)bz * C_SZ + gc0 + a_cc) * N_SZ + a_nb;

    for (int n0 = 0; n0 < N_SZ; n0 += 64) {
        __syncthreads();
        {   // stage c chunk: 8 floats/thread, hi/lo
            const float* cp = cp_base + (size_t)n0 * D_SZ;
            float4 c0 = ((const float4*)cp)[0];
            float4 c1 = ((const float4*)cp)[1];
            bf16x8 h, l;
            split8(c0, c1, &h, &l);
            *(bf16x8*)&smc_hi[c_nn * 72 + c_d0] = h;
            *(bf16x8*)&smc_lo[c_nn * 72 + c_d0] = l;
        }
        {   // stage a chunk: 32 floats/thread
            const float* ap = ap_base + n0;
#pragma unroll
            for (int q = 0; q < 4; ++q) {
                float4 a0 = ((const float4*)ap)[2 * q];
                float4 a1 = ((const float4*)ap)[2 * q + 1];
                *(bf16x8*)&sma[a_cc * 72 + a_nb + q * 8] = pack8(a0, a1);
            }
        }
        __syncthreads();

        {   // QK for this wave's n-quarter (same order as stats_kernel!)
            bf16x8 k0h = *(const bf16x8*)&smc_hi[(wch * 16 + l15) * 72 + lg * 8];
            bf16x8 k1h = *(const bf16x8*)&smc_hi[(wch * 16 + l15) * 72 + 32 + lg * 8];
            bf16x8 k0l = *(const bf16x8*)&smc_lo[(wch * 16 + l15) * 72 + lg * 8];
            bf16x8 k1l = *(const bf16x8*)&smc_lo[(wch * 16 + l15) * 72 + 32 + lg * 8];
#pragma unroll
            for (int mf = 0; mf < 4; ++mf) {
                f32x4 s = {0.f, 0.f, 0.f, 0.f};
                s = __builtin_amdgcn_mfma_f32_16x16x32_bf16(qh[mf][0], k0h, s, 0, 0, 0);
                s = __builtin_amdgcn_mfma_f32_16x16x32_bf16(qh[mf][1], k1h, s, 0, 0, 0);
                s = __builtin_amdgcn_mfma_f32_16x16x32_bf16(ql[mf][0], k0h, s, 0, 0, 0);
                s = __builtin_amdgcn_mfma_f32_16x16x32_bf16(ql[mf][1], k1h, s, 0, 0, 0);
                s = __builtin_amdgcn_mfma_f32_16x16x32_bf16(qh[mf][0], k0l, s, 0, 0, 0);
                s = __builtin_amdgcn_mfma_f32_16x16x32_bf16(qh[mf][1], k1l, s, 0, 0, 0);
#pragma unroll
                for (int r = 0; r < 4; ++r) {
                    float p = __expf(s[r] - rm[mf][r]);
                    smp[(wm * 64 + mf * 16 + lg * 4 + r) * 72 + wch * 16 + l15] = f2bf(p);
                }
            }
        }
        __syncthreads();

        // PV: acc[chf][mf] += A(a)[ch][n] * B(P)[n][m]
#pragma unroll
        for (int kf = 0; kf < 2; ++kf) {
            bf16x8 af[4], pf[4];
#pragma unroll
            for (int chf = 0; chf < 4; ++chf)
                af[chf] = *(const bf16x8*)&sma[(wch * 64 + chf * 16 + l15) * 72 + kf * 32 + lg * 8];
#pragma unroll
            for (int mf = 0; mf < 4; ++mf)
                pf[mf] = *(const bf16x8*)&smp[(wm * 64 + mf * 16 + l15) * 72 + kf * 32 + lg * 8];
#pragma unroll
            for (int chf = 0; chf < 4; ++chf)
#pragma unroll
                for (int mf = 0; mf < 4; ++mf)
                    acc[chf][mf] = __builtin_amdgcn_mfma_f32_16x16x32_bf16(
                        af[chf], pf[mf], acc[chf][mf], 0, 0, 0);
        }
    }

    // epilogue: scale by rinv, add residual a, store
    float ri[4];
#pragma unroll
    for (int mf = 0; mf < 4; ++mf)
        ri[mf] = rinv[(size_t)bz * N_SZ + mbase + mf * 16 + l15];

#pragma unroll
    for (int chf = 0; chf < 4; ++chf)
#pragma unroll
        for (int mf = 0; mf < 4; ++mf) {
            const int m = mbase + mf * 16 + l15;
#pragma unroll
            for (int r = 0; r < 4; ++r) {
                const int ch = gc0 + wch * 64 + chf * 16 + lg * 4 + r;
                size_t o = ((size_t)bz * C_SZ + ch) * N_SZ + m;
                out[o] = acc[chf][mf][r] * ri[mf] + amat[o];
            }
        }
}

extern "C" void kernel_launch(void* const* d_in, const int* in_sizes, int n_in,
                              void* d_out, int out_size, void* d_ws, size_t ws_size,
                              hipStream_t stream) {
    const float* a = (const float*)d_in[0];
    const float* b = (const float*)d_in[1];
    const float* c = (const float*)d_in[2];
    float* out = (float*)d_out;

    // partials live in d_out (overwritten later by pv_kernel); finals in ws
    float* partM = out;
    float* partL = out + (size_t)B_SZ * N_SZ * 4;
    float* rmax = (float*)d_ws;
    float* rinv = rmax + (size_t)B_SZ * N_SZ;

    stats_kernel<<<dim3(N_SZ / 256, 4, B_SZ), 256, 0, stream>>>(b, c, partM, partL);
    combine_kernel<<<dim3(B_SZ * N_SZ / 256), 256, 0, stream>>>(partM, partL, rmax, rinv);
    pv_kernel<<<dim3(N_SZ / 128, C_SZ / 256, B_SZ), 512, 0, stream>>>(
        a, b, c, rmax, rinv, out);
}

// Round 4
// 316.455 us; speedup vs baseline: 9.3608x; 1.0143x over previous
//
#include <hip/hip_runtime.h>
#include <math.h>

#define B_SZ 4
#define C_SZ 512
#define N_SZ 4096
#define D_SZ 64

typedef __attribute__((ext_vector_type(4))) float f32x4;
typedef __attribute__((ext_vector_type(8))) short bf16x8;

// fp32 -> bf16 with round-to-nearest-even
__device__ __forceinline__ short f2bf(float x) {
    union { float f; unsigned u; } v; v.f = x;
    unsigned r = v.u + 0x7FFFu + ((v.u >> 16) & 1u);
    return (short)(r >> 16);
}
__device__ __forceinline__ float bf2f(short h) {
    union { float f; unsigned u; } v; v.u = ((unsigned)(unsigned short)h) << 16;
    return v.f;
}

__device__ __forceinline__ bf16x8 pack8(float4 a, float4 b) {
    bf16x8 r;
    r[0] = f2bf(a.x); r[1] = f2bf(a.y); r[2] = f2bf(a.z); r[3] = f2bf(a.w);
    r[4] = f2bf(b.x); r[5] = f2bf(b.y); r[6] = f2bf(b.z); r[7] = f2bf(b.w);
    return r;
}

// split 8 fp32 into bf16 hi + bf16 lo (residual) — ~fp32 accuracy when recombined
__device__ __forceinline__ void split8(float4 a, float4 b, bf16x8* hi, bf16x8* lo) {
    float v[8] = {a.x, a.y, a.z, a.w, b.x, b.y, b.z, b.w};
    bf16x8 h, l;
#pragma unroll
    for (int i = 0; i < 8; ++i) {
        short hh = f2bf(v[i]);
        h[i] = hh;
        l[i] = f2bf(v[i] - bf2f(hh));
    }
    *hi = h; *lo = l;
}

// ---------------------------------------------------------------------------
// Pass 1: softmax stats with hi/lo split-bf16 scores (unchanged from R3).
// ---------------------------------------------------------------------------
__global__ __launch_bounds__(256) void stats_kernel(
    const float* __restrict__ bmat, const float* __restrict__ cmat,
    float* __restrict__ partM, float* __restrict__ partL)
{
    const int t = threadIdx.x;
    const int lane = t & 63;
    const int l15 = lane & 15;
    const int lg = lane >> 4;
    const int w = t >> 6;
    const int bz = blockIdx.z;
    const int m0 = blockIdx.x * 256 + w * 64;
    const int nbeg = blockIdx.y * 1024;

    __shared__ __align__(16) short smc_hi[64 * 72];
    __shared__ __align__(16) short smc_lo[64 * 72];

    bf16x8 qh[4][2], ql[4][2];
#pragma unroll
    for (int mf = 0; mf < 4; ++mf)
#pragma unroll
        for (int kf = 0; kf < 2; ++kf) {
            const float* qp = bmat + ((size_t)bz * N_SZ + m0 + mf * 16 + l15) * D_SZ
                              + kf * 32 + lg * 8;
            float4 q0 = ((const float4*)qp)[0];
            float4 q1 = ((const float4*)qp)[1];
            split8(q0, q1, &qh[mf][kf], &ql[mf][kf]);
        }

    float M[4][4], L[4][4];
#pragma unroll
    for (int mf = 0; mf < 4; ++mf)
#pragma unroll
        for (int r = 0; r < 4; ++r) { M[mf][r] = -1e30f; L[mf][r] = 0.0f; }

    for (int n0 = nbeg; n0 < nbeg + 1024; n0 += 64) {
        __syncthreads();
        {
            const int nn = t >> 2, d0 = (t & 3) * 16;
            const float* cp = cmat + ((size_t)bz * N_SZ + n0 + nn) * D_SZ + d0;
            float4 c0 = ((const float4*)cp)[0];
            float4 c1 = ((const float4*)cp)[1];
            float4 c2 = ((const float4*)cp)[2];
            float4 c3 = ((const float4*)cp)[3];
            bf16x8 h, l;
            split8(c0, c1, &h, &l);
            *(bf16x8*)&smc_hi[nn * 72 + d0] = h;
            *(bf16x8*)&smc_lo[nn * 72 + d0] = l;
            split8(c2, c3, &h, &l);
            *(bf16x8*)&smc_hi[nn * 72 + d0 + 8] = h;
            *(bf16x8*)&smc_lo[nn * 72 + d0 + 8] = l;
        }
        __syncthreads();

        bf16x8 kh[4][2], kl[4][2];
#pragma unroll
        for (int nf = 0; nf < 4; ++nf)
#pragma unroll
            for (int kf = 0; kf < 2; ++kf) {
                kh[nf][kf] = *(const bf16x8*)&smc_hi[(nf * 16 + l15) * 72 + kf * 32 + lg * 8];
                kl[nf][kf] = *(const bf16x8*)&smc_lo[(nf * 16 + l15) * 72 + kf * 32 + lg * 8];
            }

#pragma unroll
        for (int mf = 0; mf < 4; ++mf) {
            f32x4 sv[4];
#pragma unroll
            for (int nf = 0; nf < 4; ++nf) {
                f32x4 s = {0.f, 0.f, 0.f, 0.f};
                s = __builtin_amdgcn_mfma_f32_16x16x32_bf16(qh[mf][0], kh[nf][0], s, 0, 0, 0);
                s = __builtin_amdgcn_mfma_f32_16x16x32_bf16(qh[mf][1], kh[nf][1], s, 0, 0, 0);
                s = __builtin_amdgcn_mfma_f32_16x16x32_bf16(ql[mf][0], kh[nf][0], s, 0, 0, 0);
                s = __builtin_amdgcn_mfma_f32_16x16x32_bf16(ql[mf][1], kh[nf][1], s, 0, 0, 0);
                s = __builtin_amdgcn_mfma_f32_16x16x32_bf16(qh[mf][0], kl[nf][0], s, 0, 0, 0);
                s = __builtin_amdgcn_mfma_f32_16x16x32_bf16(qh[mf][1], kl[nf][1], s, 0, 0, 0);
                sv[nf] = s;
            }
#pragma unroll
            for (int r = 0; r < 4; ++r) {
                float cmax = fmaxf(fmaxf(sv[0][r], sv[1][r]), fmaxf(sv[2][r], sv[3][r]));
                float nm = fmaxf(M[mf][r], cmax);
                float l = L[mf][r] * __expf(M[mf][r] - nm);
                l += __expf(sv[0][r] - nm);
                l += __expf(sv[1][r] - nm);
                l += __expf(sv[2][r] - nm);
                l += __expf(sv[3][r] - nm);
                L[mf][r] = l; M[mf][r] = nm;
            }
        }
    }

#pragma unroll
    for (int mf = 0; mf < 4; ++mf)
#pragma unroll
        for (int r = 0; r < 4; ++r) {
            float m = M[mf][r], l = L[mf][r];
#pragma unroll
            for (int k = 1; k < 16; k <<= 1) {
                float mo = __shfl_xor(m, k, 64);
                float lo = __shfl_xor(l, k, 64);
                float nm = fmaxf(m, mo);
                l = l * __expf(m - nm) + lo * __expf(mo - nm);
                m = nm;
            }
            M[mf][r] = m; L[mf][r] = l;
        }

    if (l15 == 0) {
#pragma unroll
        for (int mf = 0; mf < 4; ++mf)
#pragma unroll
            for (int r = 0; r < 4; ++r) {
                int row = m0 + mf * 16 + lg * 4 + r;
                size_t idx = ((size_t)bz * N_SZ + row) * 4 + blockIdx.y;
                partM[idx] = M[mf][r];
                partL[idx] = L[mf][r];
            }
    }
}

__global__ __launch_bounds__(256) void combine_kernel(
    const float* __restrict__ partM, const float* __restrict__ partL,
    float* __restrict__ rmax, float* __restrict__ rinv)
{
    int i = blockIdx.x * 256 + threadIdx.x;
    const float* pm = partM + (size_t)i * 4;
    const float* pl = partL + (size_t)i * 4;
    float m0 = pm[0], m1 = pm[1], m2 = pm[2], m3 = pm[3];
    float m = fmaxf(fmaxf(m0, m1), fmaxf(m2, m3));
    float l = pl[0] * __expf(m0 - m) + pl[1] * __expf(m1 - m) +
              pl[2] * __expf(m2 - m) + pl[3] * __expf(m3 - m);
    rmax[i] = m;
    rinv[i] = 1.0f / l;
}

// ---------------------------------------------------------------------------
// Pass 2 (retiled): block tile = 64 m x 256 ch, 512 thr (8 waves:
// wm = w&1 -> 32-m half, wch = w>>1 -> 64-ch quarter). Grid = 512 flat,
// XCD-clustered: slice = bid&7 selects (ch-half, batch) -> all 64 m-tiles of
// one a-slice (4 MB = one XCD L2) land on one XCD -> a-refetch is L2-local.
// 2 blocks/CU (VGPR pinned <=128 via __launch_bounds__(512,4), LDS 64.5 KB).
// ---------------------------------------------------------------------------
__global__ __launch_bounds__(512, 4) void pv_kernel(
    const float* __restrict__ amat, const float* __restrict__ bmat,
    const float* __restrict__ cmat,
    const float* __restrict__ rmax, const float* __restrict__ rinv,
    float* __restrict__ out)
{
    const int t = threadIdx.x;
    const int lane = t & 63;
    const int l15 = lane & 15;
    const int lg = lane >> 4;
    const int w = t >> 6;
    const int wm = w & 1;
    const int wch = w >> 1;

    const int bid = blockIdx.x;
    const int slice = bid & 7;         // -> XCD via dispatch round-robin
    const int gm0 = (bid >> 3) * 64;   // m-tile
    const int gc0 = (slice & 1) * 256; // ch half
    const int bz = slice >> 1;         // batch

    __shared__ __align__(16) short smc_hi[64 * 72];  // c chunk [n][d] hi
    __shared__ __align__(16) short smc_lo[64 * 72];  // c chunk [n][d] lo
    __shared__ __align__(16) short sma[256 * 72];    // a chunk [ch][n]
    __shared__ __align__(16) short smp[64 * 72];     // P [m][n]

    const int mbase = gm0 + wm * 32;

    bf16x8 qh[2][2], ql[2][2];
#pragma unroll
    for (int mf = 0; mf < 2; ++mf)
#pragma unroll
        for (int kf = 0; kf < 2; ++kf) {
            const float* qp = bmat + ((size_t)bz * N_SZ + mbase + mf * 16 + l15) * D_SZ
                              + kf * 32 + lg * 8;
            float4 q0 = ((const float4*)qp)[0];
            float4 q1 = ((const float4*)qp)[1];
            split8(q0, q1, &qh[mf][kf], &ql[mf][kf]);
        }

    float rm[2][4];
#pragma unroll
    for (int mf = 0; mf < 2; ++mf)
#pragma unroll
        for (int r = 0; r < 4; ++r)
            rm[mf][r] = rmax[(size_t)bz * N_SZ + mbase + mf * 16 + lg * 4 + r];

    f32x4 acc[4][2];
#pragma unroll
    for (int i = 0; i < 4; ++i)
#pragma unroll
        for (int j = 0; j < 2; ++j)
            acc[i][j] = (f32x4){0.f, 0.f, 0.f, 0.f};

    const int c_nn = t >> 3, c_d0 = (t & 7) * 8;
    const int a_cc = t >> 1, a_nb = (t & 1) * 32;
    const float* cp_base = cmat + ((size_t)bz * N_SZ + c_nn) * D_SZ + c_d0;
    const float* ap_base = amat + ((size_t)bz * C_SZ + gc0 + a_cc) * N_SZ + a_nb;

    for (int n0 = 0; n0 < N_SZ; n0 += 64) {
        __syncthreads();
        {   // stage c chunk: 8 floats/thread, hi/lo
            const float* cp = cp_base + (size_t)n0 * D_SZ;
            float4 c0 = ((const float4*)cp)[0];
            float4 c1 = ((const float4*)cp)[1];
            bf16x8 h, l;
            split8(c0, c1, &h, &l);
            *(bf16x8*)&smc_hi[c_nn * 72 + c_d0] = h;
            *(bf16x8*)&smc_lo[c_nn * 72 + c_d0] = l;
        }
        {   // stage a chunk: 32 floats/thread
            const float* ap = ap_base + n0;
#pragma unroll
            for (int q = 0; q < 4; ++q) {
                float4 a0 = ((const float4*)ap)[2 * q];
                float4 a1 = ((const float4*)ap)[2 * q + 1];
                *(bf16x8*)&sma[a_cc * 72 + a_nb + q * 8] = pack8(a0, a1);
            }
        }
        __syncthreads();

        {   // QK for this wave's (32-m half x 16-n quarter), same MFMA order as stats
            bf16x8 k0h = *(const bf16x8*)&smc_hi[(wch * 16 + l15) * 72 + lg * 8];
            bf16x8 k1h = *(const bf16x8*)&smc_hi[(wch * 16 + l15) * 72 + 32 + lg * 8];
            bf16x8 k0l = *(const bf16x8*)&smc_lo[(wch * 16 + l15) * 72 + lg * 8];
            bf16x8 k1l = *(const bf16x8*)&smc_lo[(wch * 16 + l15) * 72 + 32 + lg * 8];
#pragma unroll
            for (int mf = 0; mf < 2; ++mf) {
                f32x4 s = {0.f, 0.f, 0.f, 0.f};
                s = __builtin_amdgcn_mfma_f32_16x16x32_bf16(qh[mf][0], k0h, s, 0, 0, 0);
                s = __builtin_amdgcn_mfma_f32_16x16x32_bf16(qh[mf][1], k1h, s, 0, 0, 0);
                s = __builtin_amdgcn_mfma_f32_16x16x32_bf16(ql[mf][0], k0h, s, 0, 0, 0);
                s = __builtin_amdgcn_mfma_f32_16x16x32_bf16(ql[mf][1], k1h, s, 0, 0, 0);
                s = __builtin_amdgcn_mfma_f32_16x16x32_bf16(qh[mf][0], k0l, s, 0, 0, 0);
                s = __builtin_amdgcn_mfma_f32_16x16x32_bf16(qh[mf][1], k1l, s, 0, 0, 0);
#pragma unroll
                for (int r = 0; r < 4; ++r) {
                    float p = __expf(s[r] - rm[mf][r]);
                    smp[(wm * 32 + mf * 16 + lg * 4 + r) * 72 + wch * 16 + l15] = f2bf(p);
                }
            }
        }
        __syncthreads();

        // PV: acc[chf][mf] += A(a)[ch][n] * B(P)[n][m]
#pragma unroll
        for (int kf = 0; kf < 2; ++kf) {
            bf16x8 pf[2];
#pragma unroll
            for (int mf = 0; mf < 2; ++mf)
                pf[mf] = *(const bf16x8*)&smp[(wm * 32 + mf * 16 + l15) * 72 + kf * 32 + lg * 8];
#pragma unroll
            for (int chf = 0; chf < 4; ++chf) {
                bf16x8 af = *(const bf16x8*)&sma[(wch * 64 + chf * 16 + l15) * 72 + kf * 32 + lg * 8];
#pragma unroll
                for (int mf = 0; mf < 2; ++mf)
                    acc[chf][mf] = __builtin_amdgcn_mfma_f32_16x16x32_bf16(
                        af, pf[mf], acc[chf][mf], 0, 0, 0);
            }
        }
    }

    // epilogue: scale by rinv, add residual a, store
    float ri[2];
#pragma unroll
    for (int mf = 0; mf < 2; ++mf)
        ri[mf] = rinv[(size_t)bz * N_SZ + mbase + mf * 16 + l15];

#pragma unroll
    for (int chf = 0; chf < 4; ++chf)
#pragma unroll
        for (int mf = 0; mf < 2; ++mf) {
            const int m = mbase + mf * 16 + l15;
#pragma unroll
            for (int r = 0; r < 4; ++r) {
                const int ch = gc0 + wch * 64 + chf * 16 + lg * 4 + r;
                size_t o = ((size_t)bz * C_SZ + ch) * N_SZ + m;
                out[o] = acc[chf][mf][r] * ri[mf] + amat[o];
            }
        }
}

extern "C" void kernel_launch(void* const* d_in, const int* in_sizes, int n_in,
                              void* d_out, int out_size, void* d_ws, size_t ws_size,
                              hipStream_t stream) {
    const float* a = (const float*)d_in[0];
    const float* b = (const float*)d_in[1];
    const float* c = (const float*)d_in[2];
    float* out = (float*)d_out;

    // partials live in d_out (overwritten later by pv_kernel); finals in ws
    float* partM = out;
    float* partL = out + (size_t)B_SZ * N_SZ * 4;
    float* rmax = (float*)d_ws;
    float* rinv = rmax + (size_t)B_SZ * N_SZ;

    stats_kernel<<<dim3(N_SZ / 256, 4, B_SZ), 256, 0, stream>>>(b, c, partM, partL);
    combine_kernel<<<dim3(B_SZ * N_SZ / 256), 256, 0, stream>>>(partM, partL, rmax, rinv);
    pv_kernel<<<dim3(512), 512, 0, stream>>>(a, b, c, rmax, rinv, out);
}

// Round 6
// 313.972 us; speedup vs baseline: 9.4349x; 1.0079x over previous
//
#include <hip/hip_runtime.h>
#include <hip/hip_bf16.h>
#include <math.h>

#define B_SZ 4
#define C_SZ 512
#define N_SZ 4096
#define D_SZ 64

typedef __attribute__((ext_vector_type(4))) float f32x4;
typedef __attribute__((ext_vector_type(8))) short bf16x8;

// fp32 -> bf16 RNE via native convert (v_cvt_pk_bf16_f32 pairs)
__device__ __forceinline__ short f2bf(float x) {
    return (short)__bfloat16_as_ushort(__float2bfloat16(x));
}
__device__ __forceinline__ float bf2f(short h) {
    union { float f; unsigned u; } v; v.u = ((unsigned)(unsigned short)h) << 16;
    return v.f;
}

__device__ __forceinline__ bf16x8 pack8(float4 a, float4 b) {
    bf16x8 r;
    r[0] = f2bf(a.x); r[1] = f2bf(a.y); r[2] = f2bf(a.z); r[3] = f2bf(a.w);
    r[4] = f2bf(b.x); r[5] = f2bf(b.y); r[6] = f2bf(b.z); r[7] = f2bf(b.w);
    return r;
}

// split 8 fp32 into bf16 hi + bf16 lo (residual) — ~fp32 accuracy recombined
__device__ __forceinline__ void split8(float4 a, float4 b, bf16x8* hi, bf16x8* lo) {
    float v[8] = {a.x, a.y, a.z, a.w, b.x, b.y, b.z, b.w};
    bf16x8 h, l;
#pragma unroll
    for (int i = 0; i < 8; ++i) {
        short hh = f2bf(v[i]);
        h[i] = hh;
        l[i] = f2bf(v[i] - bf2f(hh));
    }
    *hi = h; *lo = l;
}

// ---------------------------------------------------------------------------
// Pass 1: softmax stats with hi/lo split-bf16 scores.
// ---------------------------------------------------------------------------
__global__ __launch_bounds__(256) void stats_kernel(
    const float* __restrict__ bmat, const float* __restrict__ cmat,
    float* __restrict__ partM, float* __restrict__ partL)
{
    const int t = threadIdx.x;
    const int lane = t & 63;
    const int l15 = lane & 15;
    const int lg = lane >> 4;
    const int w = t >> 6;
    const int bz = blockIdx.z;
    const int m0 = blockIdx.x * 256 + w * 64;
    const int nbeg = blockIdx.y * 1024;

    __shared__ __align__(16) short smc_hi[64 * 72];
    __shared__ __align__(16) short smc_lo[64 * 72];

    bf16x8 qh[4][2], ql[4][2];
#pragma unroll
    for (int mf = 0; mf < 4; ++mf)
#pragma unroll
        for (int kf = 0; kf < 2; ++kf) {
            const float* qp = bmat + ((size_t)bz * N_SZ + m0 + mf * 16 + l15) * D_SZ
                              + kf * 32 + lg * 8;
            float4 q0 = ((const float4*)qp)[0];
            float4 q1 = ((const float4*)qp)[1];
            split8(q0, q1, &qh[mf][kf], &ql[mf][kf]);
        }

    float M[4][4], L[4][4];
#pragma unroll
    for (int mf = 0; mf < 4; ++mf)
#pragma unroll
        for (int r = 0; r < 4; ++r) { M[mf][r] = -1e30f; L[mf][r] = 0.0f; }

    for (int n0 = nbeg; n0 < nbeg + 1024; n0 += 64) {
        __syncthreads();
        {
            const int nn = t >> 2, d0 = (t & 3) * 16;
            const float* cp = cmat + ((size_t)bz * N_SZ + n0 + nn) * D_SZ + d0;
            float4 c0 = ((const float4*)cp)[0];
            float4 c1 = ((const float4*)cp)[1];
            float4 c2 = ((const float4*)cp)[2];
            float4 c3 = ((const float4*)cp)[3];
            bf16x8 h, l;
            split8(c0, c1, &h, &l);
            *(bf16x8*)&smc_hi[nn * 72 + d0] = h;
            *(bf16x8*)&smc_lo[nn * 72 + d0] = l;
            split8(c2, c3, &h, &l);
            *(bf16x8*)&smc_hi[nn * 72 + d0 + 8] = h;
            *(bf16x8*)&smc_lo[nn * 72 + d0 + 8] = l;
        }
        __syncthreads();

        bf16x8 kh[4][2], kl[4][2];
#pragma unroll
        for (int nf = 0; nf < 4; ++nf)
#pragma unroll
            for (int kf = 0; kf < 2; ++kf) {
                kh[nf][kf] = *(const bf16x8*)&smc_hi[(nf * 16 + l15) * 72 + kf * 32 + lg * 8];
                kl[nf][kf] = *(const bf16x8*)&smc_lo[(nf * 16 + l15) * 72 + kf * 32 + lg * 8];
            }

#pragma unroll
        for (int mf = 0; mf < 4; ++mf) {
            f32x4 sv[4];
#pragma unroll
            for (int nf = 0; nf < 4; ++nf) {
                f32x4 s = {0.f, 0.f, 0.f, 0.f};
                s = __builtin_amdgcn_mfma_f32_16x16x32_bf16(qh[mf][0], kh[nf][0], s, 0, 0, 0);
                s = __builtin_amdgcn_mfma_f32_16x16x32_bf16(qh[mf][1], kh[nf][1], s, 0, 0, 0);
                s = __builtin_amdgcn_mfma_f32_16x16x32_bf16(ql[mf][0], kh[nf][0], s, 0, 0, 0);
                s = __builtin_amdgcn_mfma_f32_16x16x32_bf16(ql[mf][1], kh[nf][1], s, 0, 0, 0);
                s = __builtin_amdgcn_mfma_f32_16x16x32_bf16(qh[mf][0], kl[nf][0], s, 0, 0, 0);
                s = __builtin_amdgcn_mfma_f32_16x16x32_bf16(qh[mf][1], kl[nf][1], s, 0, 0, 0);
                sv[nf] = s;
            }
#pragma unroll
            for (int r = 0; r < 4; ++r) {
                float cmax = fmaxf(fmaxf(sv[0][r], sv[1][r]), fmaxf(sv[2][r], sv[3][r]));
                float nm = fmaxf(M[mf][r], cmax);
                float l = L[mf][r] * __expf(M[mf][r] - nm);
                l += __expf(sv[0][r] - nm);
                l += __expf(sv[1][r] - nm);
                l += __expf(sv[2][r] - nm);
                l += __expf(sv[3][r] - nm);
                L[mf][r] = l; M[mf][r] = nm;
            }
        }
    }

#pragma unroll
    for (int mf = 0; mf < 4; ++mf)
#pragma unroll
        for (int r = 0; r < 4; ++r) {
            float m = M[mf][r], l = L[mf][r];
#pragma unroll
            for (int k = 1; k < 16; k <<= 1) {
                float mo = __shfl_xor(m, k, 64);
                float lo = __shfl_xor(l, k, 64);
                float nm = fmaxf(m, mo);
                l = l * __expf(m - nm) + lo * __expf(mo - nm);
                m = nm;
            }
            M[mf][r] = m; L[mf][r] = l;
        }

    if (l15 == 0) {
#pragma unroll
        for (int mf = 0; mf < 4; ++mf)
#pragma unroll
            for (int r = 0; r < 4; ++r) {
                int row = m0 + mf * 16 + lg * 4 + r;
                size_t idx = ((size_t)bz * N_SZ + row) * 4 + blockIdx.y;
                partM[idx] = M[mf][r];
                partL[idx] = L[mf][r];
            }
    }
}

__global__ __launch_bounds__(256) void combine_kernel(
    const float* __restrict__ partM, const float* __restrict__ partL,
    float* __restrict__ rmax, float* __restrict__ rinv)
{
    int i = blockIdx.x * 256 + threadIdx.x;
    const float* pm = partM + (size_t)i * 4;
    const float* pl = partL + (size_t)i * 4;
    float m0 = pm[0], m1 = pm[1], m2 = pm[2], m3 = pm[3];
    float m = fmaxf(fmaxf(m0, m1), fmaxf(m2, m3));
    float l = pl[0] * __expf(m0 - m) + pl[1] * __expf(m1 - m) +
              pl[2] * __expf(m2 - m) + pl[3] * __expf(m3 - m);
    rmax[i] = m;
    rinv[i] = 1.0f / l;
}

// ---------------------------------------------------------------------------
// Pass 2: block = 256 thr (4 waves), tile 256ch x 64m, wave tile 64ch x 64m
// (acc[4][4]). Wave w also owns the 16-n QK strip nf = w. Grid = 512 flat,
// XCD-clustered (slice = bid&7 -> (ch-half, batch)). 2 blocks/CU.
// ---------------------------------------------------------------------------
__global__ __launch_bounds__(256, 2) void pv_kernel(
    const float* __restrict__ amat, const float* __restrict__ bmat,
    const float* __restrict__ cmat,
    const float* __restrict__ rmax, const float* __restrict__ rinv,
    float* __restrict__ out)
{
    const int t = threadIdx.x;
    const int lane = t & 63;
    const int l15 = lane & 15;
    const int lg = lane >> 4;
    const int w = t >> 6;

    const int bid = blockIdx.x;
    const int slice = bid & 7;         // -> XCD via dispatch round-robin
    const int gm0 = (bid >> 3) * 64;   // m-tile
    const int gc0 = (slice & 1) * 256; // ch half
    const int bz = slice >> 1;         // batch

    __shared__ __align__(16) short smc_hi[64 * 72];  // c chunk [n][d] hi
    __shared__ __align__(16) short smc_lo[64 * 72];  // c chunk [n][d] lo
    __shared__ __align__(16) short sma[256 * 72];    // a chunk [ch][n]
    __shared__ __align__(16) short smp[64 * 72];     // P [m][n]

    // Q fragments for all 4 m-frags of this block's 64 m-rows
    bf16x8 qh[4][2], ql[4][2];
#pragma unroll
    for (int mf = 0; mf < 4; ++mf)
#pragma unroll
        for (int kf = 0; kf < 2; ++kf) {
            const float* qp = bmat + ((size_t)bz * N_SZ + gm0 + mf * 16 + l15) * D_SZ
                              + kf * 32 + lg * 8;
            float4 q0 = ((const float4*)qp)[0];
            float4 q1 = ((const float4*)qp)[1];
            split8(q0, q1, &qh[mf][kf], &ql[mf][kf]);
        }

    float rm[4][4];
#pragma unroll
    for (int mf = 0; mf < 4; ++mf)
#pragma unroll
        for (int r = 0; r < 4; ++r)
            rm[mf][r] = rmax[(size_t)bz * N_SZ + gm0 + mf * 16 + lg * 4 + r];

    f32x4 acc[4][4];
#pragma unroll
    for (int i = 0; i < 4; ++i)
#pragma unroll
        for (int j = 0; j < 4; ++j)
            acc[i][j] = (f32x4){0.f, 0.f, 0.f, 0.f};

    const int c_nn = t >> 2, c_d0 = (t & 3) * 16;
    const float* cp_base = cmat + ((size_t)bz * N_SZ + c_nn) * D_SZ + c_d0;
    const float* ap_base = amat + ((size_t)bz * C_SZ + gc0 + t) * N_SZ;

    for (int n0 = 0; n0 < N_SZ; n0 += 64) {
        __syncthreads();
        {   // stage c chunk: 16 floats/thread, hi/lo
            const float* cp = cp_base + (size_t)n0 * D_SZ;
            float4 c0 = ((const float4*)cp)[0];
            float4 c1 = ((const float4*)cp)[1];
            float4 c2 = ((const float4*)cp)[2];
            float4 c3 = ((const float4*)cp)[3];
            bf16x8 h, l;
            split8(c0, c1, &h, &l);
            *(bf16x8*)&smc_hi[c_nn * 72 + c_d0] = h;
            *(bf16x8*)&smc_lo[c_nn * 72 + c_d0] = l;
            split8(c2, c3, &h, &l);
            *(bf16x8*)&smc_hi[c_nn * 72 + c_d0 + 8] = h;
            *(bf16x8*)&smc_lo[c_nn * 72 + c_d0 + 8] = l;
        }
        {   // stage a chunk: one ch row per thread, 64 floats (q < 8!)
            const float* ap = ap_base + n0;
#pragma unroll
            for (int q = 0; q < 8; ++q) {
                float4 a0 = ((const float4*)ap)[2 * q];
                float4 a1 = ((const float4*)ap)[2 * q + 1];
                *(bf16x8*)&sma[t * 72 + q * 8] = pack8(a0, a1);
            }
        }
        __syncthreads();

        {   // QK: wave w owns n-strip nf = w (16 n), all 4 m-frags
            bf16x8 k0h = *(const bf16x8*)&smc_hi[(w * 16 + l15) * 72 + lg * 8];
            bf16x8 k1h = *(const bf16x8*)&smc_hi[(w * 16 + l15) * 72 + 32 + lg * 8];
            bf16x8 k0l = *(const bf16x8*)&smc_lo[(w * 16 + l15) * 72 + lg * 8];
            bf16x8 k1l = *(const bf16x8*)&smc_lo[(w * 16 + l15) * 72 + 32 + lg * 8];
#pragma unroll
            for (int mf = 0; mf < 4; ++mf) {
                f32x4 s = {0.f, 0.f, 0.f, 0.f};
                s = __builtin_amdgcn_mfma_f32_16x16x32_bf16(qh[mf][0], k0h, s, 0, 0, 0);
                s = __builtin_amdgcn_mfma_f32_16x16x32_bf16(qh[mf][1], k1h, s, 0, 0, 0);
                s = __builtin_amdgcn_mfma_f32_16x16x32_bf16(ql[mf][0], k0h, s, 0, 0, 0);
                s = __builtin_amdgcn_mfma_f32_16x16x32_bf16(ql[mf][1], k1h, s, 0, 0, 0);
                s = __builtin_amdgcn_mfma_f32_16x16x32_bf16(qh[mf][0], k0l, s, 0, 0, 0);
                s = __builtin_amdgcn_mfma_f32_16x16x32_bf16(qh[mf][1], k1l, s, 0, 0, 0);
#pragma unroll
                for (int r = 0; r < 4; ++r) {
                    float p = __expf(s[r] - rm[mf][r]);
                    smp[(mf * 16 + lg * 4 + r) * 72 + w * 16 + l15] = f2bf(p);
                }
            }
        }
        __syncthreads();

        // PV: acc[chf][mf] += A(a)[ch][n] * B(P)[n][m]
#pragma unroll
        for (int kf = 0; kf < 2; ++kf) {
            bf16x8 pf[4], af[4];
#pragma unroll
            for (int mf = 0; mf < 4; ++mf)
                pf[mf] = *(const bf16x8*)&smp[(mf * 16 + l15) * 72 + kf * 32 + lg * 8];
#pragma unroll
            for (int chf = 0; chf < 4; ++chf)
                af[chf] = *(const bf16x8*)&sma[(w * 64 + chf * 16 + l15) * 72 + kf * 32 + lg * 8];
#pragma unroll
            for (int chf = 0; chf < 4; ++chf)
#pragma unroll
                for (int mf = 0; mf < 4; ++mf)
                    acc[chf][mf] = __builtin_amdgcn_mfma_f32_16x16x32_bf16(
                        af[chf], pf[mf], acc[chf][mf], 0, 0, 0);
        }
    }

    // epilogue: scale by rinv, add residual a, store
    float ri[4];
#pragma unroll
    for (int mf = 0; mf < 4; ++mf)
        ri[mf] = rinv[(size_t)bz * N_SZ + gm0 + mf * 16 + l15];

#pragma unroll
    for (int chf = 0; chf < 4; ++chf)
#pragma unroll
        for (int mf = 0; mf < 4; ++mf) {
            const int m = gm0 + mf * 16 + l15;
#pragma unroll
            for (int r = 0; r < 4; ++r) {
                const int ch = gc0 + w * 64 + chf * 16 + lg * 4 + r;
                size_t o = ((size_t)bz * C_SZ + ch) * N_SZ + m;
                out[o] = acc[chf][mf][r] * ri[mf] + amat[o];
            }
        }
}

extern "C" void kernel_launch(void* const* d_in, const int* in_sizes, int n_in,
                              void* d_out, int out_size, void* d_ws, size_t ws_size,
                              hipStream_t stream) {
    const float* a = (const float*)d_in[0];
    const float* b = (const float*)d_in[1];
    const float* c = (const float*)d_in[2];
    float* out = (float*)d_out;

    // partials live in d_out (overwritten later by pv_kernel); finals in ws
    float* partM = out;
    float* partL = out + (size_t)B_SZ * N_SZ * 4;
    float* rmax = (float*)d_ws;
    float* rinv = rmax + (size_t)B_SZ * N_SZ;

    stats_kernel<<<dim3(N_SZ / 256, 4, B_SZ), 256, 0, stream>>>(b, c, partM, partL);
    combine_kernel<<<dim3(B_SZ * N_SZ / 256), 256, 0, stream>>>(partM, partL, rmax, rinv);
    pv_kernel<<<dim3(512), 256, 0, stream>>>(a, b, c, rmax, rinv, out);
}

// Round 7
// 265.464 us; speedup vs baseline: 11.1589x; 1.1827x over previous
//
#include <hip/hip_runtime.h>
#include <hip/hip_bf16.h>
#include <math.h>

#define B_SZ 4
#define C_SZ 512
#define N_SZ 4096
#define D_SZ 64

typedef __attribute__((ext_vector_type(4))) float f32x4;
typedef __attribute__((ext_vector_type(8))) short bf16x8;

// fp32 -> bf16 RNE via native convert
__device__ __forceinline__ short f2bf(float x) {
    return (short)__bfloat16_as_ushort(__float2bfloat16(x));
}
__device__ __forceinline__ float bf2f(short h) {
    union { float f; unsigned u; } v; v.u = ((unsigned)(unsigned short)h) << 16;
    return v.f;
}

__device__ __forceinline__ bf16x8 pack8(float4 a, float4 b) {
    bf16x8 r;
    r[0] = f2bf(a.x); r[1] = f2bf(a.y); r[2] = f2bf(a.z); r[3] = f2bf(a.w);
    r[4] = f2bf(b.x); r[5] = f2bf(b.y); r[6] = f2bf(b.z); r[7] = f2bf(b.w);
    return r;
}

__device__ __forceinline__ void split8(float4 a, float4 b, bf16x8* hi, bf16x8* lo) {
    float v[8] = {a.x, a.y, a.z, a.w, b.x, b.y, b.z, b.w};
    bf16x8 h, l;
#pragma unroll
    for (int i = 0; i < 8; ++i) {
        short hh = f2bf(v[i]);
        h[i] = hh;
        l[i] = f2bf(v[i] - bf2f(hh));
    }
    *hi = h; *lo = l;
}

// ---------------------------------------------------------------------------
// Pre-pass: a fp32 -> bf16 (RNE, same rounding as pack8)
// ---------------------------------------------------------------------------
__global__ __launch_bounds__(256) void conv_a_kernel(
    const float* __restrict__ amat, short* __restrict__ abf)
{
    size_t i = ((size_t)blockIdx.x * 256 + threadIdx.x) * 8;
    float4 a0 = ((const float4*)(amat + i))[0];
    float4 a1 = ((const float4*)(amat + i))[1];
    *(bf16x8*)(abf + i) = pack8(a0, a1);
}

// Pre-pass: c fp32 -> bf16 hi/lo (same split as split8)
__global__ __launch_bounds__(256) void conv_c_kernel(
    const float* __restrict__ cmat, short* __restrict__ chi, short* __restrict__ clo)
{
    size_t i = ((size_t)blockIdx.x * 256 + threadIdx.x) * 8;
    float4 c0 = ((const float4*)(cmat + i))[0];
    float4 c1 = ((const float4*)(cmat + i))[1];
    bf16x8 h, l;
    split8(c0, c1, &h, &l);
    *(bf16x8*)(chi + i) = h;
    *(bf16x8*)(clo + i) = l;
}

// ---------------------------------------------------------------------------
// Pass 1: softmax stats with hi/lo split-bf16 scores (proven, unchanged).
// ---------------------------------------------------------------------------
__global__ __launch_bounds__(256) void stats_kernel(
    const float* __restrict__ bmat, const float* __restrict__ cmat,
    float* __restrict__ partM, float* __restrict__ partL)
{
    const int t = threadIdx.x;
    const int lane = t & 63;
    const int l15 = lane & 15;
    const int lg = lane >> 4;
    const int w = t >> 6;
    const int bz = blockIdx.z;
    const int m0 = blockIdx.x * 256 + w * 64;
    const int nbeg = blockIdx.y * 1024;

    __shared__ __align__(16) short smc_hi[64 * 72];
    __shared__ __align__(16) short smc_lo[64 * 72];

    bf16x8 qh[4][2], ql[4][2];
#pragma unroll
    for (int mf = 0; mf < 4; ++mf)
#pragma unroll
        for (int kf = 0; kf < 2; ++kf) {
            const float* qp = bmat + ((size_t)bz * N_SZ + m0 + mf * 16 + l15) * D_SZ
                              + kf * 32 + lg * 8;
            float4 q0 = ((const float4*)qp)[0];
            float4 q1 = ((const float4*)qp)[1];
            split8(q0, q1, &qh[mf][kf], &ql[mf][kf]);
        }

    float M[4][4], L[4][4];
#pragma unroll
    for (int mf = 0; mf < 4; ++mf)
#pragma unroll
        for (int r = 0; r < 4; ++r) { M[mf][r] = -1e30f; L[mf][r] = 0.0f; }

    for (int n0 = nbeg; n0 < nbeg + 1024; n0 += 64) {
        __syncthreads();
        {
            const int nn = t >> 2, d0 = (t & 3) * 16;
            const float* cp = cmat + ((size_t)bz * N_SZ + n0 + nn) * D_SZ + d0;
            float4 c0 = ((const float4*)cp)[0];
            float4 c1 = ((const float4*)cp)[1];
            float4 c2 = ((const float4*)cp)[2];
            float4 c3 = ((const float4*)cp)[3];
            bf16x8 h, l;
            split8(c0, c1, &h, &l);
            *(bf16x8*)&smc_hi[nn * 72 + d0] = h;
            *(bf16x8*)&smc_lo[nn * 72 + d0] = l;
            split8(c2, c3, &h, &l);
            *(bf16x8*)&smc_hi[nn * 72 + d0 + 8] = h;
            *(bf16x8*)&smc_lo[nn * 72 + d0 + 8] = l;
        }
        __syncthreads();

        bf16x8 kh[4][2], kl[4][2];
#pragma unroll
        for (int nf = 0; nf < 4; ++nf)
#pragma unroll
            for (int kf = 0; kf < 2; ++kf) {
                kh[nf][kf] = *(const bf16x8*)&smc_hi[(nf * 16 + l15) * 72 + kf * 32 + lg * 8];
                kl[nf][kf] = *(const bf16x8*)&smc_lo[(nf * 16 + l15) * 72 + kf * 32 + lg * 8];
            }

#pragma unroll
        for (int mf = 0; mf < 4; ++mf) {
            f32x4 sv[4];
#pragma unroll
            for (int nf = 0; nf < 4; ++nf) {
                f32x4 s = {0.f, 0.f, 0.f, 0.f};
                s = __builtin_amdgcn_mfma_f32_16x16x32_bf16(qh[mf][0], kh[nf][0], s, 0, 0, 0);
                s = __builtin_amdgcn_mfma_f32_16x16x32_bf16(qh[mf][1], kh[nf][1], s, 0, 0, 0);
                s = __builtin_amdgcn_mfma_f32_16x16x32_bf16(ql[mf][0], kh[nf][0], s, 0, 0, 0);
                s = __builtin_amdgcn_mfma_f32_16x16x32_bf16(ql[mf][1], kh[nf][1], s, 0, 0, 0);
                s = __builtin_amdgcn_mfma_f32_16x16x32_bf16(qh[mf][0], kl[nf][0], s, 0, 0, 0);
                s = __builtin_amdgcn_mfma_f32_16x16x32_bf16(qh[mf][1], kl[nf][1], s, 0, 0, 0);
                sv[nf] = s;
            }
#pragma unroll
            for (int r = 0; r < 4; ++r) {
                float cmax = fmaxf(fmaxf(sv[0][r], sv[1][r]), fmaxf(sv[2][r], sv[3][r]));
                float nm = fmaxf(M[mf][r], cmax);
                float l = L[mf][r] * __expf(M[mf][r] - nm);
                l += __expf(sv[0][r] - nm);
                l += __expf(sv[1][r] - nm);
                l += __expf(sv[2][r] - nm);
                l += __expf(sv[3][r] - nm);
                L[mf][r] = l; M[mf][r] = nm;
            }
        }
    }

#pragma unroll
    for (int mf = 0; mf < 4; ++mf)
#pragma unroll
        for (int r = 0; r < 4; ++r) {
            float m = M[mf][r], l = L[mf][r];
#pragma unroll
            for (int k = 1; k < 16; k <<= 1) {
                float mo = __shfl_xor(m, k, 64);
                float lo = __shfl_xor(l, k, 64);
                float nm = fmaxf(m, mo);
                l = l * __expf(m - nm) + lo * __expf(mo - nm);
                m = nm;
            }
            M[mf][r] = m; L[mf][r] = l;
        }

    if (l15 == 0) {
#pragma unroll
        for (int mf = 0; mf < 4; ++mf)
#pragma unroll
            for (int r = 0; r < 4; ++r) {
                int row = m0 + mf * 16 + lg * 4 + r;
                size_t idx = ((size_t)bz * N_SZ + row) * 4 + blockIdx.y;
                partM[idx] = M[mf][r];
                partL[idx] = L[mf][r];
            }
    }
}

__global__ __launch_bounds__(256) void combine_kernel(
    const float* __restrict__ partM, const float* __restrict__ partL,
    float* __restrict__ rmax, float* __restrict__ rinv)
{
    int i = blockIdx.x * 256 + threadIdx.x;
    const float* pm = partM + (size_t)i * 4;
    const float* pl = partL + (size_t)i * 4;
    float m0 = pm[0], m1 = pm[1], m2 = pm[2], m3 = pm[3];
    float m = fmaxf(fmaxf(m0, m1), fmaxf(m2, m3));
    float l = pl[0] * __expf(m0 - m) + pl[1] * __expf(m1 - m) +
              pl[2] * __expf(m2 - m) + pl[3] * __expf(m3 - m);
    rmax[i] = m;
    rinv[i] = 1.0f / l;
}

// ---------------------------------------------------------------------------
// Pass 2 v2: NO input staging. A/K MFMA fragments loaded directly from
// pre-converted bf16 global (L2-resident via XCD-clustered slice). Only P
// goes through LDS (double-buffered) -> ONE barrier per 64-key chunk, and
// QK(k+1) overlaps PV(k). Block 256 thr (4 waves), tile 256ch x 64m.
// ---------------------------------------------------------------------------
__global__ __launch_bounds__(256, 2) void pv2_kernel(
    const float* __restrict__ amat, const float* __restrict__ bmat,
    const short* __restrict__ abf, const short* __restrict__ chi,
    const short* __restrict__ clo,
    const float* __restrict__ rmax, const float* __restrict__ rinv,
    float* __restrict__ out)
{
    const int t = threadIdx.x;
    const int lane = t & 63;
    const int l15 = lane & 15;
    const int lg = lane >> 4;
    const int w = t >> 6;

    const int bid = blockIdx.x;
    const int slice = bid & 7;         // -> XCD via dispatch round-robin
    const int gm0 = (bid >> 3) * 64;   // m-tile
    const int gc0 = (slice & 1) * 256; // ch half
    const int bz = slice >> 1;         // batch

    __shared__ __align__(16) short smp[2][64 * 72];  // P [m][n], double-buffered

    // Q fragments (fp32 -> hi/lo split in regs, once per block)
    bf16x8 qh[4][2], ql[4][2];
#pragma unroll
    for (int mf = 0; mf < 4; ++mf)
#pragma unroll
        for (int kf = 0; kf < 2; ++kf) {
            const float* qp = bmat + ((size_t)bz * N_SZ + gm0 + mf * 16 + l15) * D_SZ
                              + kf * 32 + lg * 8;
            float4 q0 = ((const float4*)qp)[0];
            float4 q1 = ((const float4*)qp)[1];
            split8(q0, q1, &qh[mf][kf], &ql[mf][kf]);
        }

    float rm[4][4];
#pragma unroll
    for (int mf = 0; mf < 4; ++mf)
#pragma unroll
        for (int r = 0; r < 4; ++r)
            rm[mf][r] = rmax[(size_t)bz * N_SZ + gm0 + mf * 16 + lg * 4 + r];

    f32x4 acc[4][4];
#pragma unroll
    for (int i = 0; i < 4; ++i)
#pragma unroll
        for (int j = 0; j < 4; ++j)
            acc[i][j] = (f32x4){0.f, 0.f, 0.f, 0.f};

    // K-fragment base: c row (w*16 + l15), d-octet lg*8
    const short* kb_hi = chi + ((size_t)bz * N_SZ + w * 16 + l15) * D_SZ + lg * 8;
    const short* kb_lo = clo + ((size_t)bz * N_SZ + w * 16 + l15) * D_SZ + lg * 8;
    // A-fragment base: a row (gc0 + w*64 + l15), n-octet lg*8
    const short* ab = abf + ((size_t)bz * C_SZ + gc0 + w * 64 + l15) * N_SZ + lg * 8;

    // QK for chunk starting at n0, write P into smp[pbuf]
    auto QK = [&](int n0, int pbuf) {
        const short* kh = kb_hi + (size_t)n0 * D_SZ;
        const short* kl = kb_lo + (size_t)n0 * D_SZ;
        bf16x8 k0h = *(const bf16x8*)(kh);
        bf16x8 k1h = *(const bf16x8*)(kh + 32);
        bf16x8 k0l = *(const bf16x8*)(kl);
        bf16x8 k1l = *(const bf16x8*)(kl + 32);
#pragma unroll
        for (int mf = 0; mf < 4; ++mf) {
            f32x4 s = {0.f, 0.f, 0.f, 0.f};
            s = __builtin_amdgcn_mfma_f32_16x16x32_bf16(qh[mf][0], k0h, s, 0, 0, 0);
            s = __builtin_amdgcn_mfma_f32_16x16x32_bf16(qh[mf][1], k1h, s, 0, 0, 0);
            s = __builtin_amdgcn_mfma_f32_16x16x32_bf16(ql[mf][0], k0h, s, 0, 0, 0);
            s = __builtin_amdgcn_mfma_f32_16x16x32_bf16(ql[mf][1], k1h, s, 0, 0, 0);
            s = __builtin_amdgcn_mfma_f32_16x16x32_bf16(qh[mf][0], k0l, s, 0, 0, 0);
            s = __builtin_amdgcn_mfma_f32_16x16x32_bf16(qh[mf][1], k1l, s, 0, 0, 0);
#pragma unroll
            for (int r = 0; r < 4; ++r) {
                float p = __expf(s[r] - rm[mf][r]);
                smp[pbuf][(mf * 16 + lg * 4 + r) * 72 + w * 16 + l15] = f2bf(p);
            }
        }
    };

    // PV for chunk n0 reading smp[pbuf]
    auto PV = [&](int n0, int pbuf) {
#pragma unroll
        for (int kf = 0; kf < 2; ++kf) {
            bf16x8 pf[4], af[4];
#pragma unroll
            for (int mf = 0; mf < 4; ++mf)
                pf[mf] = *(const bf16x8*)&smp[pbuf][(mf * 16 + l15) * 72 + kf * 32 + lg * 8];
#pragma unroll
            for (int chf = 0; chf < 4; ++chf)
                af[chf] = *(const bf16x8*)(ab + (size_t)chf * 16 * N_SZ + n0 + kf * 32);
#pragma unroll
            for (int chf = 0; chf < 4; ++chf)
#pragma unroll
                for (int mf = 0; mf < 4; ++mf)
                    acc[chf][mf] = __builtin_amdgcn_mfma_f32_16x16x32_bf16(
                        af[chf], pf[mf], acc[chf][mf], 0, 0, 0);
        }
    };

    QK(0, 0);
    for (int k = 0; k < 63; ++k) {
        __syncthreads();
        PV(k * 64, k & 1);
        QK((k + 1) * 64, (k + 1) & 1);
    }
    __syncthreads();
    PV(63 * 64, 1);

    // epilogue: scale by rinv, add residual a, store
    float ri[4];
#pragma unroll
    for (int mf = 0; mf < 4; ++mf)
        ri[mf] = rinv[(size_t)bz * N_SZ + gm0 + mf * 16 + l15];

#pragma unroll
    for (int chf = 0; chf < 4; ++chf)
#pragma unroll
        for (int mf = 0; mf < 4; ++mf) {
            const int m = gm0 + mf * 16 + l15;
#pragma unroll
            for (int r = 0; r < 4; ++r) {
                const int ch = gc0 + w * 64 + chf * 16 + lg * 4 + r;
                size_t o = ((size_t)bz * C_SZ + ch) * N_SZ + m;
                out[o] = acc[chf][mf][r] * ri[mf] + amat[o];
            }
        }
}

// ---------------------------------------------------------------------------
// Fallback pass 2 (R6, proven): used only if ws_size is too small.
// ---------------------------------------------------------------------------
__global__ __launch_bounds__(256, 2) void pv_kernel(
    const float* __restrict__ amat, const float* __restrict__ bmat,
    const float* __restrict__ cmat,
    const float* __restrict__ rmax, const float* __restrict__ rinv,
    float* __restrict__ out)
{
    const int t = threadIdx.x;
    const int lane = t & 63;
    const int l15 = lane & 15;
    const int lg = lane >> 4;
    const int w = t >> 6;

    const int bid = blockIdx.x;
    const int slice = bid & 7;
    const int gm0 = (bid >> 3) * 64;
    const int gc0 = (slice & 1) * 256;
    const int bz = slice >> 1;

    __shared__ __align__(16) short smc_hi[64 * 72];
    __shared__ __align__(16) short smc_lo[64 * 72];
    __shared__ __align__(16) short sma[256 * 72];
    __shared__ __align__(16) short smp[64 * 72];

    bf16x8 qh[4][2], ql[4][2];
#pragma unroll
    for (int mf = 0; mf < 4; ++mf)
#pragma unroll
        for (int kf = 0; kf < 2; ++kf) {
            const float* qp = bmat + ((size_t)bz * N_SZ + gm0 + mf * 16 + l15) * D_SZ
                              + kf * 32 + lg * 8;
            float4 q0 = ((const float4*)qp)[0];
            float4 q1 = ((const float4*)qp)[1];
            split8(q0, q1, &qh[mf][kf], &ql[mf][kf]);
        }

    float rm[4][4];
#pragma unroll
    for (int mf = 0; mf < 4; ++mf)
#pragma unroll
        for (int r = 0; r < 4; ++r)
            rm[mf][r] = rmax[(size_t)bz * N_SZ + gm0 + mf * 16 + lg * 4 + r];

    f32x4 acc[4][4];
#pragma unroll
    for (int i = 0; i < 4; ++i)
#pragma unroll
        for (int j = 0; j < 4; ++j)
            acc[i][j] = (f32x4){0.f, 0.f, 0.f, 0.f};

    const int c_nn = t >> 2, c_d0 = (t & 3) * 16;
    const float* cp_base = cmat + ((size_t)bz * N_SZ + c_nn) * D_SZ + c_d0;
    const float* ap_base = amat + ((size_t)bz * C_SZ + gc0 + t) * N_SZ;

    for (int n0 = 0; n0 < N_SZ; n0 += 64) {
        __syncthreads();
        {
            const float* cp = cp_base + (size_t)n0 * D_SZ;
            float4 c0 = ((const float4*)cp)[0];
            float4 c1 = ((const float4*)cp)[1];
            float4 c2 = ((const float4*)cp)[2];
            float4 c3 = ((const float4*)cp)[3];
            bf16x8 h, l;
            split8(c0, c1, &h, &l);
            *(bf16x8*)&smc_hi[c_nn * 72 + c_d0] = h;
            *(bf16x8*)&smc_lo[c_nn * 72 + c_d0] = l;
            split8(c2, c3, &h, &l);
            *(bf16x8*)&smc_hi[c_nn * 72 + c_d0 + 8] = h;
            *(bf16x8*)&smc_lo[c_nn * 72 + c_d0 + 8] = l;
        }
        {
            const float* ap = ap_base + n0;
#pragma unroll
            for (int q = 0; q < 8; ++q) {
                float4 a0 = ((const float4*)ap)[2 * q];
                float4 a1 = ((const float4*)ap)[2 * q + 1];
                *(bf16x8*)&sma[t * 72 + q * 8] = pack8(a0, a1);
            }
        }
        __syncthreads();

        {
            bf16x8 k0h = *(const bf16x8*)&smc_hi[(w * 16 + l15) * 72 + lg * 8];
            bf16x8 k1h = *(const bf16x8*)&smc_hi[(w * 16 + l15) * 72 + 32 + lg * 8];
            bf16x8 k0l = *(const bf16x8*)&smc_lo[(w * 16 + l15) * 72 + lg * 8];
            bf16x8 k1l = *(const bf16x8*)&smc_lo[(w * 16 + l15) * 72 + 32 + lg * 8];
#pragma unroll
            for (int mf = 0; mf < 4; ++mf) {
                f32x4 s = {0.f, 0.f, 0.f, 0.f};
                s = __builtin_amdgcn_mfma_f32_16x16x32_bf16(qh[mf][0], k0h, s, 0, 0, 0);
                s = __builtin_amdgcn_mfma_f32_16x16x32_bf16(qh[mf][1], k1h, s, 0, 0, 0);
                s = __builtin_amdgcn_mfma_f32_16x16x32_bf16(ql[mf][0], k0h, s, 0, 0, 0);
                s = __builtin_amdgcn_mfma_f32_16x16x32_bf16(ql[mf][1], k1h, s, 0, 0, 0);
                s = __builtin_amdgcn_mfma_f32_16x16x32_bf16(qh[mf][0], k0l, s, 0, 0, 0);
                s = __builtin_amdgcn_mfma_f32_16x16x32_bf16(qh[mf][1], k1l, s, 0, 0, 0);
#pragma unroll
                for (int r = 0; r < 4; ++r) {
                    float p = __expf(s[r] - rm[mf][r]);
                    smp[(mf * 16 + lg * 4 + r) * 72 + w * 16 + l15] = f2bf(p);
                }
            }
        }
        __syncthreads();

#pragma unroll
        for (int kf = 0; kf < 2; ++kf) {
            bf16x8 pf[4], af[4];
#pragma unroll
            for (int mf = 0; mf < 4; ++mf)
                pf[mf] = *(const bf16x8*)&smp[(mf * 16 + l15) * 72 + kf * 32 + lg * 8];
#pragma unroll
            for (int chf = 0; chf < 4; ++chf)
                af[chf] = *(const bf16x8*)&sma[(w * 64 + chf * 16 + l15) * 72 + kf * 32 + lg * 8];
#pragma unroll
            for (int chf = 0; chf < 4; ++chf)
#pragma unroll
                for (int mf = 0; mf < 4; ++mf)
                    acc[chf][mf] = __builtin_amdgcn_mfma_f32_16x16x32_bf16(
                        af[chf], pf[mf], acc[chf][mf], 0, 0, 0);
        }
    }

    float ri[4];
#pragma unroll
    for (int mf = 0; mf < 4; ++mf)
        ri[mf] = rinv[(size_t)bz * N_SZ + gm0 + mf * 16 + l15];

#pragma unroll
    for (int chf = 0; chf < 4; ++chf)
#pragma unroll
        for (int mf = 0; mf < 4; ++mf) {
            const int m = gm0 + mf * 16 + l15;
#pragma unroll
            for (int r = 0; r < 4; ++r) {
                const int ch = gc0 + w * 64 + chf * 16 + lg * 4 + r;
                size_t o = ((size_t)bz * C_SZ + ch) * N_SZ + m;
                out[o] = acc[chf][mf][r] * ri[mf] + amat[o];
            }
        }
}

extern "C" void kernel_launch(void* const* d_in, const int* in_sizes, int n_in,
                              void* d_out, int out_size, void* d_ws, size_t ws_size,
                              hipStream_t stream) {
    const float* a = (const float*)d_in[0];
    const float* b = (const float*)d_in[1];
    const float* c = (const float*)d_in[2];
    float* out = (float*)d_out;

    // partials live in d_out (overwritten later by pv kernels)
    float* partM = out;
    float* partL = out + (size_t)B_SZ * N_SZ * 4;

    // ws layout: rmax | rinv | abf | chi | clo
    const size_t rmax_b = (size_t)B_SZ * N_SZ * 4;
    const size_t abf_b  = (size_t)B_SZ * C_SZ * N_SZ * 2;
    const size_t c_b    = (size_t)B_SZ * N_SZ * D_SZ * 2;
    const size_t need   = 2 * rmax_b + abf_b + 2 * c_b;

    float* rmax = (float*)d_ws;
    float* rinv = (float*)((char*)d_ws + rmax_b);

    stats_kernel<<<dim3(N_SZ / 256, 4, B_SZ), 256, 0, stream>>>(b, c, partM, partL);
    combine_kernel<<<dim3(B_SZ * N_SZ / 256), 256, 0, stream>>>(partM, partL, rmax, rinv);

    if (ws_size >= need) {
        short* abf = (short*)((char*)d_ws + 2 * rmax_b);
        short* chi = (short*)((char*)d_ws + 2 * rmax_b + abf_b);
        short* clo = (short*)((char*)d_ws + 2 * rmax_b + abf_b + c_b);

        conv_a_kernel<<<dim3((B_SZ * C_SZ * N_SZ) / (256 * 8)), 256, 0, stream>>>(a, abf);
        conv_c_kernel<<<dim3((B_SZ * N_SZ * D_SZ) / (256 * 8)), 256, 0, stream>>>(c, chi, clo);
        pv2_kernel<<<dim3(512), 256, 0, stream>>>(a, b, abf, chi, clo, rmax, rinv, out);
    } else {
        pv_kernel<<<dim3(512), 256, 0, stream>>>(a, b, c, rmax, rinv, out);
    }
}